// Round 8
// baseline (259.933 us; speedup 1.0000x reference)
//
#include <hip/hip_runtime.h>

typedef float f2 __attribute__((ext_vector_type(2)));
typedef float f4 __attribute__((ext_vector_type(4)));

#define PAD 5
#define WSZ 11

// Precomputed normalized 11-tap Gaussian (sigma=1.5) — matches fp32 ref far
// within the 1.4e-2 threshold. Hard-coded to keep weights out of VGPRs.
__device__ __forceinline__ float gw(int k) {
    const float G[WSZ] = {
        0.0010283782f, 0.0075987580f, 0.0360007600f, 0.1093607000f,
        0.2130055600f, 0.2660117400f,
        0.2130055600f, 0.1093607000f, 0.0360007600f, 0.0075987580f, 0.0010283782f };
    return G[k];
}

// Pyramid pre-pass (R5-proven, ~22us): one wave per (col-half, 8-row group,
// channel) = 6144 waves. Lane owns 4 CONTIGUOUS cols -> every global load is
// a fully-coalesced wave-wide f4; all 16 loads issued up-front. Produces p1
// (2x2), p2 (4x4), p3 (8x8 via one __shfl_xor pair-reduce).
__global__ __launch_bounds__(64) void pyramid_kernel(
    const float* __restrict__ img1, const float* __restrict__ img2,
    f2* __restrict__ p1, f2* __restrict__ p2, f2* __restrict__ p3)
{
    const int lane = threadIdx.x;        // owns raw cols cb*256 + lane*4 ..+3
    const int cb = blockIdx.x;           // column half (0/1)
    const int rb = blockIdx.y;           // 8-row group (0..63)
    const int z  = blockIdx.z;

    const size_t ibase = (size_t)z * 262144 + (size_t)(rb * 8) * 512 + cb * 256 + lane * 4;
    const float* b1 = img1 + ibase;
    const float* b2 = img2 + ibase;

    f4 A[8], B[8];
#pragma unroll
    for (int r = 0; r < 8; ++r) {        // 16 independent loads in flight
        A[r] = *(const f4*)(b1 + r * 512);
        B[r] = *(const f4*)(b2 + r * 512);
    }

    f2 u0, u1;
#pragma unroll
    for (int q = 0; q < 2; ++q) {        // q = p2 row within group
        f2 acc = {0.f, 0.f};
#pragma unroll
        for (int h = 0; h < 2; ++h) {    // p1 row within p2 row
            const int rp = q * 2 + h;
            f4 a0 = A[2 * rp], a1 = A[2 * rp + 1];
            f4 c0 = B[2 * rp], c1 = B[2 * rp + 1];
            f2 v0 = { (a0.x + a0.y + a1.x + a1.y) * 0.25f,
                      (c0.x + c0.y + c1.x + c1.y) * 0.25f };
            f2 v1 = { (a0.z + a0.w + a1.z + a1.w) * 0.25f,
                      (c0.z + c0.w + c1.z + c1.w) * 0.25f };
            *(f4*)(p1 + (size_t)z * 65536 + (size_t)(rb * 4 + rp) * 256
                       + cb * 128 + lane * 2) = (f4){ v0.x, v0.y, v1.x, v1.y };
            acc += v0 + v1;
        }
        f2 u = acc * 0.25f;              // p2 pixel (4x4 avg)
        p2[(size_t)z * 16384 + (size_t)(rb * 2 + q) * 128 + cb * 64 + lane] = u;
        if (q == 0) u0 = u; else u1 = u;
    }
    f2 t = u0 + u1;                       // lane's 2 p2 pixels
    t.x += __shfl_xor(t.x, 1);            // + neighbor lane's column
    t.y += __shfl_xor(t.y, 1);
    if ((lane & 1) == 0)
        p3[(size_t)z * 4096 + (size_t)rb * 64 + cb * 32 + (lane >> 1)] = t * 0.25f;
}

// Per-wave SSIM strip body, 2-ROW-PER-ITERATION version (R8).
// 64-col x RT-row strip. Each iteration stages and filters a PAIR of rows:
// two independent H-filter chains interleave in one tap loop (2x intra-wave
// ILP), fences/barriers and loop bookkeeping halve per row, and the pair-
// depth-2 prefetch keeps 4 rows in flight. VALU ops/row and LDS ops/row are
// UNCHANGED vs R5 (R7 lesson: trading VALU for LDS traffic loses; R2/R6
// lesson: occupancy levers lose — latency/ILP is the remaining lever).
// Horizontal 11-tap via two 80-wide private LDS rows (same-wave DS ordering;
// wavefront fences pin the compiler, emit no waitcnt -> prefetch loads stay
// in flight). Vertical 11-tap via a 12-deep register ring; ring slot of
// staged row r is r%12 = 2*j2+parity — static after the unroll-by-6 (12 rows
// per outer iteration, same ring period as R5).
// [R4 lesson: pooling-at-consume destroys the prefetch structure — s1-3
//  MUST read precomputed pyramid buffers.]
template<int RT, bool PLANAR>
__device__ __forceinline__ float ssim_body(
    const float* __restrict__ img1, const float* __restrict__ img2,
    const f2* __restrict__ pair,
    int H, int W, int bx, int sy, int z, f2* st, int lane)
{
    const int ox = bx * 64;
    const int r0 = sy * RT;
    const size_t base = (size_t)z * H * W;

    constexpr int NIT  = RT + 10;        // staged rows (even: RT even)
    constexpr int NIT2 = NIT / 2;        // row pairs
    const float C1 = 1e-4f, C2 = 9e-4f;

    // Per-lane column geometry (iteration-invariant).
    const int c0 = ox - PAD + lane;
    const bool m0 = (c0 >= 0) & (c0 < W);
    const int c0c = min(max(c0, 0), W - 1);
    const int c1 = ox + 59 + lane;                 // halo cols, lanes 0..9
    const bool m1 = (lane < 10) & (c1 < W);
    const int c1c = min(c1, W - 1);

    // Two prefetch slots, each holding a ROW PAIR (a=main col, b=halo col).
    f2 P0a0={0.f,0.f}, P0a1={0.f,0.f}, P0b0={0.f,0.f}, P0b1={0.f,0.f};
    f2 P1a0={0.f,0.f}, P1a1={0.f,0.f}, P1b0={0.f,0.f}, P1b1={0.f,0.f};

    auto issue2 = [&](int y, f2& A0, f2& A1, f2& B0, f2& B1) {
        const int ya = min(max(y, 0), H - 1);          // clamp; mask at consume
        const int yb = min(max(y + 1, 0), H - 1);
        const size_t ra = base + (size_t)ya * W;       // wave-uniform -> SALU
        const size_t rb = base + (size_t)yb * W;
        if (PLANAR) {
            A0 = (f2){ img1[ra + c0c], img2[ra + c0c] };
            A1 = (f2){ img1[rb + c0c], img2[rb + c0c] };
            if (lane < 10) {
                B0 = (f2){ img1[ra + c1c], img2[ra + c1c] };
                B1 = (f2){ img1[rb + c1c], img2[rb + c1c] };
            }
        } else {
            A0 = pair[ra + c0c];
            A1 = pair[rb + c0c];
            if (lane < 10) { B0 = pair[ra + c1c]; B1 = pair[rb + c1c]; }
        }
    };

    issue2(r0 - PAD + 0, P0a0, P0a1, P0b0, P0b1);   // pair 0
    issue2(r0 - PAD + 2, P1a0, P1a1, P1b0, P1b1);   // pair 1

    f2 rmu[12], rsq[12];
    float rxx[12];
    float local = 0.f;
    const f2 zero = {0.f, 0.f};
    f2* st0 = st;          // staging row for even staged-row index
    f2* st1 = st + 80;     // staging row for odd staged-row index

#pragma clang loop unroll(disable)
    for (int q0 = 0; q0 < NIT2; q0 += 6) {
#pragma unroll
        for (int j2 = 0; j2 < 6; ++j2) {
            const int i2 = q0 + j2;
            if (i2 < NIT2) {
                const int it0 = 2 * i2;                // absolute staged-row idx
                const int y0 = r0 - PAD + it0;
                const bool yok0 = (y0 >= 0) & (y0 < H);      // wave-uniform
                const bool yok1 = (y0 + 1 >= 0) & (y0 + 1 < H);

                f2& a0 = (j2 & 1) ? P1a0 : P0a0;       // static slot select
                f2& a1 = (j2 & 1) ? P1a1 : P0a1;
                f2& b0 = (j2 & 1) ? P1b0 : P0b0;
                f2& b1 = (j2 & 1) ? P1b1 : P0b1;
                f2 wa0 = (yok0 & m0) ? a0 : zero;      // vmcnt wait lands here
                f2 wa1 = (yok1 & m0) ? a1 : zero;
                f2 wb0 = (yok0 & m1) ? b0 : zero;
                f2 wb1 = (yok1 & m1) ? b1 : zero;
                issue2(y0 + 4, a0, a1, b0, b1);        // refill: 2 pairs in flight

                __builtin_amdgcn_fence(__ATOMIC_ACQ_REL, "wavefront");
                __builtin_amdgcn_wave_barrier();
                st0[lane] = wa0;
                st1[lane] = wa1;
                if (lane < 10) { st0[64 + lane] = wb0; st1[64 + lane] = wb1; }
                __builtin_amdgcn_fence(__ATOMIC_ACQ_REL, "wavefront");
                __builtin_amdgcn_wave_barrier();

                // Horizontal 11-tap for BOTH rows, interleaved (independent
                // chains -> 2x ILP). Same-wave DS ordering guarantees RAW.
                f2 hmu0 = zero, hsq0 = zero, hmu1 = zero, hsq1 = zero;
                float hxx0 = 0.f, hxx1 = 0.f;
#pragma unroll
                for (int k = 0; k < WSZ; ++k) {
                    const float g = gw(k);
                    f2 p0 = st0[lane + k];
                    f2 p1 = st1[lane + k];
                    hmu0 += p0 * g;  hsq0 += (p0 * p0) * g;  hxx0 += (p0.x * p0.y) * g;
                    hmu1 += p1 * g;  hsq1 += (p1 * p1) * g;  hxx1 += (p1.x * p1.y) * g;
                }
                const int sE = 2 * j2;                 // staged row it0 slot
                const int sO = 2 * j2 + 1;             // staged row it0+1 slot
                rmu[sE] = hmu0; rsq[sE] = hsq0; rxx[sE] = hxx0;
                rmu[sO] = hmu1; rsq[sO] = hsq1; rxx[sO] = hxx1;

                // Vertical 11-tap + SSIM for the two completed output rows
                // (o0 = it0-10 needs slots (2*j2+2+k)%12; o1 = it0-9 needs
                // (2*j2+3+k)%12 — both static after unroll).
                if (it0 >= 10) {
                    f2 vmu0 = zero, vsq0 = zero, vmu1 = zero, vsq1 = zero;
                    float vxx0 = 0.f, vxx1 = 0.f;
#pragma unroll
                    for (int k = 0; k < WSZ; ++k) {
                        const float g = gw(k);
                        const int sA = (2 * j2 + 2 + k) % 12;
                        const int sB = (2 * j2 + 3 + k) % 12;
                        vmu0 += rmu[sA] * g; vsq0 += rsq[sA] * g; vxx0 += rxx[sA] * g;
                        vmu1 += rmu[sB] * g; vsq1 += rsq[sB] * g; vxx1 += rxx[sB] * g;
                    }
                    {
                        const float mu1 = vmu0.x, mu2 = vmu0.y;
                        const float mu11 = mu1 * mu1, mu22 = mu2 * mu2, mu12 = mu1 * mu2;
                        const float sig1 = vsq0.x - mu11;
                        const float sig2 = vsq0.y - mu22;
                        const float sig12 = vxx0 - mu12;
                        const float num = (2.f * mu12 + C1) * (2.f * sig12 + C2);
                        const float den = (mu11 + mu22 + C1) * (sig1 + sig2 + C2);
                        local += num * __builtin_amdgcn_rcpf(den);
                    }
                    {
                        const float mu1 = vmu1.x, mu2 = vmu1.y;
                        const float mu11 = mu1 * mu1, mu22 = mu2 * mu2, mu12 = mu1 * mu2;
                        const float sig1 = vsq1.x - mu11;
                        const float sig2 = vsq1.y - mu22;
                        const float sig12 = vxx1 - mu12;
                        const float num = (2.f * mu12 + C1) * (2.f * sig12 + C2);
                        const float den = (mu11 + mu22 + C1) * (sig1 + sig2 + C2);
                        local += num * __builtin_amdgcn_rcpf(den);
                    }
                }
            }
        }
    }

#pragma unroll
    for (int off = 32; off > 0; off >>= 1) local += __shfl_down(local, off);
    return local;
}

// All 4 scales in ONE dispatch (R5 structure). 128-thread blocks = 2
// independent waves on adjacent row strips. Scales interleaved in groups of
// 29 (16:8:4:1 matches per-channel block counts 32:16:8:2) so every scale is
// co-resident from t=0; small scales run inside scale-0's shadow.
// Each wave plain-stores its partial to its own slot -> no init kernel, no
// atomics, no device fences (R6 lesson: per-block threadfence+atomics cost
// ~80us of stall). __launch_bounds__(128,4): 128-VGPR cap — est. usage ~80
// (an 85-VGPR cap spilled the vertical ring: 2.2x slower — watch FETCH_SIZE
// for the spill signature).
__global__ __launch_bounds__(128, 4) void ssim_fused_kernel(
    const float* __restrict__ img1, const float* __restrict__ img2,
    const f2* __restrict__ p1, const f2* __restrict__ p2, const f2* __restrict__ p3,
    double* __restrict__ partials)
{
    __shared__ f2 st_all[2][160];          // per wave: 2 staging rows x 80
    const int lane = threadIdx.x & 63;
    const int wv   = threadIdx.x >> 6;
    f2* st = st_all[wv];

    const int i = blockIdx.x;
    const int g = i / 29;                  // magic-mul div
    const int r = i - g * 29;

    float local;
    if (r < 16) {                          // scale 0: RT=64, 512x512, planar
        const int l = g * 16 + r;
        local = ssim_body<64, true>(img1, img2, nullptr, 512, 512,
                                    l & 7, ((l >> 3) & 3) * 2 + wv, l >> 5, st, lane);
    } else if (r < 24) {                   // scale 1: RT=32, 256x256
        const int l = g * 8 + (r - 16);
        local = ssim_body<32, false>(nullptr, nullptr, p1, 256, 256,
                                     l & 3, ((l >> 2) & 3) * 2 + wv, l >> 4, st, lane);
    } else if (r < 28) {                   // scale 2: RT=16, 128x128
        const int l = g * 4 + (r - 24);
        local = ssim_body<16, false>(nullptr, nullptr, p2, 128, 128,
                                     l & 1, ((l >> 1) & 3) * 2 + wv, l >> 3, st, lane);
    } else {                               // scale 3: RT=16, 64x64
        const int l = g;
        local = ssim_body<16, false>(nullptr, nullptr, p3, 64, 64,
                                     0, (l & 1) * 2 + wv, l >> 1, st, lane);
    }
    if (lane == 0) partials[(size_t)i * 2 + wv] = (double)local;
}

// Single-block reduce of all per-wave partials; decodes wave->scale from the
// same group-of-29 mapping. ~45 KB of L2-hot doubles, few us.
__global__ __launch_bounds__(256) void finalize_kernel(
    const double* __restrict__ partials, float* __restrict__ out, int nw,
    double c0, double c1, double c2, double c3)
{
    double s[4] = {0.0, 0.0, 0.0, 0.0};
    for (int idx = threadIdx.x; idx < nw; idx += 256) {
        const int b = idx >> 1;
        const int g = b / 29;
        const int r = b - g * 29;
        const int sc = (r < 16) ? 0 : (r < 24) ? 1 : (r < 28) ? 2 : 3;
        s[sc] += partials[idx];
    }
    __shared__ double sm[4][256];
    sm[0][threadIdx.x] = s[0]; sm[1][threadIdx.x] = s[1];
    sm[2][threadIdx.x] = s[2]; sm[3][threadIdx.x] = s[3];
    __syncthreads();
    if (threadIdx.x == 0) {
        const double w[4] = {0.0448, 0.2856, 0.3001, 0.2363};
        const double cnt[4] = {c0, c1, c2, c3};
        double loss = 0.0;
#pragma unroll
        for (int sc = 0; sc < 4; ++sc) {
            double t = 0.0;
            for (int k = 0; k < 256; ++k) t += sm[sc][k];
            loss += w[sc] * (1.0 - t / cnt[sc]);
        }
        out[0] = (float)loss;
    }
}

extern "C" void kernel_launch(void* const* d_in, const int* in_sizes, int n_in,
                              void* d_out, int out_size, void* d_ws, size_t ws_size,
                              hipStream_t stream) {
    const float* img1 = (const float*)d_in[0];
    const float* img2 = (const float*)d_in[1];
    float* out = (float*)d_out;

    const int H0 = 512, W0 = 512;
    const int NC = in_sizes[0] / (H0 * W0);  // 48

    double* partials = (double*)d_ws;                 // NC*58*2 doubles (<64KB)
    f2* p1 = (f2*)((char*)d_ws + 65536);              // NC*256*256
    f2* p2 = p1 + (size_t)NC * 256 * 256;             // NC*128*128
    f2* p3 = p2 + (size_t)NC * 128 * 128;             // NC*64*64

    // Pyramid: 2 col-halves x 64 row-groups x NC channels, 1 wave each.
    pyramid_kernel<<<dim3(2, 64, NC), 64, 0, stream>>>(img1, img2, p1, p2, p3);

    // Fused SSIM: per channel 32+16+8+2 = 58 blocks = 2 groups of 29.
    const int NBLK = NC * 58;
    ssim_fused_kernel<<<dim3(NBLK), 128, 0, stream>>>(img1, img2, p1, p2, p3, partials);

    const double c0 = (double)NC * 512.0 * 512.0;
    const double c1 = (double)NC * 256.0 * 256.0;
    const double c2 = (double)NC * 128.0 * 128.0;
    const double c3 = (double)NC * 64.0 * 64.0;
    finalize_kernel<<<1, 256, 0, stream>>>(partials, out, NBLK * 2, c0, c1, c2, c3);
}

// Round 9
// 237.816 us; speedup vs baseline: 1.0930x; 1.0930x over previous
//
#include <hip/hip_runtime.h>

typedef float f2 __attribute__((ext_vector_type(2)));
typedef float f4 __attribute__((ext_vector_type(4)));

#define PAD 5
#define WSZ 11

// Precomputed normalized 11-tap Gaussian (sigma=1.5) — matches fp32 ref far
// within the 1.4e-2 threshold. Hard-coded to keep weights out of VGPRs.
__device__ __forceinline__ float gw(int k) {
    const float G[WSZ] = {
        0.0010283782f, 0.0075987580f, 0.0360007600f, 0.1093607000f,
        0.2130055600f, 0.2660117400f,
        0.2130055600f, 0.1093607000f, 0.0360007600f, 0.0075987580f, 0.0010283782f };
    return G[k];
}

// Pyramid pre-pass (R5-proven, ~22us): one wave per (col-half, 8-row group,
// channel) = 6144 waves. Lane owns 4 CONTIGUOUS cols -> every global load is
// a fully-coalesced wave-wide f4; all 16 loads issued up-front. Produces p1
// (2x2), p2 (4x4), p3 (8x8 via one __shfl_xor pair-reduce).
__global__ __launch_bounds__(64) void pyramid_kernel(
    const float* __restrict__ img1, const float* __restrict__ img2,
    f2* __restrict__ p1, f2* __restrict__ p2, f2* __restrict__ p3)
{
    const int lane = threadIdx.x;        // owns raw cols cb*256 + lane*4 ..+3
    const int cb = blockIdx.x;           // column half (0/1)
    const int rb = blockIdx.y;           // 8-row group (0..63)
    const int z  = blockIdx.z;

    const size_t ibase = (size_t)z * 262144 + (size_t)(rb * 8) * 512 + cb * 256 + lane * 4;
    const float* b1 = img1 + ibase;
    const float* b2 = img2 + ibase;

    f4 A[8], B[8];
#pragma unroll
    for (int r = 0; r < 8; ++r) {        // 16 independent loads in flight
        A[r] = *(const f4*)(b1 + r * 512);
        B[r] = *(const f4*)(b2 + r * 512);
    }

    f2 u0, u1;
#pragma unroll
    for (int q = 0; q < 2; ++q) {        // q = p2 row within group
        f2 acc = {0.f, 0.f};
#pragma unroll
        for (int h = 0; h < 2; ++h) {    // p1 row within p2 row
            const int rp = q * 2 + h;
            f4 a0 = A[2 * rp], a1 = A[2 * rp + 1];
            f4 c0 = B[2 * rp], c1 = B[2 * rp + 1];
            f2 v0 = { (a0.x + a0.y + a1.x + a1.y) * 0.25f,
                      (c0.x + c0.y + c1.x + c1.y) * 0.25f };
            f2 v1 = { (a0.z + a0.w + a1.z + a1.w) * 0.25f,
                      (c0.z + c0.w + c1.z + c1.w) * 0.25f };
            *(f4*)(p1 + (size_t)z * 65536 + (size_t)(rb * 4 + rp) * 256
                       + cb * 128 + lane * 2) = (f4){ v0.x, v0.y, v1.x, v1.y };
            acc += v0 + v1;
        }
        f2 u = acc * 0.25f;              // p2 pixel (4x4 avg)
        p2[(size_t)z * 16384 + (size_t)(rb * 2 + q) * 128 + cb * 64 + lane] = u;
        if (q == 0) u0 = u; else u1 = u;
    }
    f2 t = u0 + u1;                       // lane's 2 p2 pixels
    t.x += __shfl_xor(t.x, 1);            // + neighbor lane's column
    t.y += __shfl_xor(t.y, 1);
    if ((lane & 1) == 0)
        p3[(size_t)z * 4096 + (size_t)rb * 64 + cb * 32 + (lane >> 1)] = t * 0.25f;
}

// Per-wave SSIM strip body, 2-ROW-PER-ITERATION version (R8/R9).
// 64-col x RT-row strip. Each iteration stages and filters a PAIR of rows:
// two independent H-filter chains interleave in one tap loop (2x intra-wave
// ILP), fences/barriers and loop bookkeeping halve per row, and the pair-
// depth-2 prefetch keeps 4 rows in flight. VALU ops/row and LDS ops/row are
// UNCHANGED vs R5 (R7 lesson: trading VALU for LDS traffic loses; R2/R6
// lesson: occupancy levers lose — latency/ILP is the remaining lever).
// Horizontal 11-tap via two 80-wide private LDS rows (same-wave DS ordering;
// wavefront fences pin the compiler, emit no waitcnt -> prefetch loads stay
// in flight). Vertical 11-tap via a 12-deep register ring; ring slot of
// staged row r is r%12 = 2*j2+parity — static after the unroll-by-6 (12 rows
// per outer iteration, same ring period as R5).
// [R4 lesson: pooling-at-consume destroys the prefetch structure — s1-3
//  MUST read precomputed pyramid buffers.]
template<int RT, bool PLANAR>
__device__ __forceinline__ float ssim_body(
    const float* __restrict__ img1, const float* __restrict__ img2,
    const f2* __restrict__ pair,
    int H, int W, int bx, int sy, int z, f2* st, int lane)
{
    const int ox = bx * 64;
    const int r0 = sy * RT;
    const size_t base = (size_t)z * H * W;

    constexpr int NIT  = RT + 10;        // staged rows (even: RT even)
    constexpr int NIT2 = NIT / 2;        // row pairs
    const float C1 = 1e-4f, C2 = 9e-4f;

    // Per-lane column geometry (iteration-invariant).
    const int c0 = ox - PAD + lane;
    const bool m0 = (c0 >= 0) & (c0 < W);
    const int c0c = min(max(c0, 0), W - 1);
    const int c1 = ox + 59 + lane;                 // halo cols, lanes 0..9
    const bool m1 = (lane < 10) & (c1 < W);
    const int c1c = min(c1, W - 1);

    // Two prefetch slots, each holding a ROW PAIR (a=main col, b=halo col).
    f2 P0a0={0.f,0.f}, P0a1={0.f,0.f}, P0b0={0.f,0.f}, P0b1={0.f,0.f};
    f2 P1a0={0.f,0.f}, P1a1={0.f,0.f}, P1b0={0.f,0.f}, P1b1={0.f,0.f};

    auto issue2 = [&](int y, f2& A0, f2& A1, f2& B0, f2& B1) {
        const int ya = min(max(y, 0), H - 1);          // clamp; mask at consume
        const int yb = min(max(y + 1, 0), H - 1);
        const size_t ra = base + (size_t)ya * W;       // wave-uniform -> SALU
        const size_t rb = base + (size_t)yb * W;
        if (PLANAR) {
            A0 = (f2){ img1[ra + c0c], img2[ra + c0c] };
            A1 = (f2){ img1[rb + c0c], img2[rb + c0c] };
            if (lane < 10) {
                B0 = (f2){ img1[ra + c1c], img2[ra + c1c] };
                B1 = (f2){ img1[rb + c1c], img2[rb + c1c] };
            }
        } else {
            A0 = pair[ra + c0c];
            A1 = pair[rb + c0c];
            if (lane < 10) { B0 = pair[ra + c1c]; B1 = pair[rb + c1c]; }
        }
    };

    issue2(r0 - PAD + 0, P0a0, P0a1, P0b0, P0b1);   // pair 0
    issue2(r0 - PAD + 2, P1a0, P1a1, P1b0, P1b1);   // pair 1

    f2 rmu[12], rsq[12];
    float rxx[12];
    float local = 0.f;
    const f2 zero = {0.f, 0.f};
    f2* st0 = st;          // staging row for even staged-row index
    f2* st1 = st + 80;     // staging row for odd staged-row index

#pragma clang loop unroll(disable)
    for (int q0 = 0; q0 < NIT2; q0 += 6) {
#pragma unroll
        for (int j2 = 0; j2 < 6; ++j2) {
            const int i2 = q0 + j2;
            if (i2 < NIT2) {
                const int it0 = 2 * i2;                // absolute staged-row idx
                const int y0 = r0 - PAD + it0;
                const bool yok0 = (y0 >= 0) & (y0 < H);      // wave-uniform
                const bool yok1 = (y0 + 1 >= 0) & (y0 + 1 < H);

                f2& a0 = (j2 & 1) ? P1a0 : P0a0;       // static slot select
                f2& a1 = (j2 & 1) ? P1a1 : P0a1;
                f2& b0 = (j2 & 1) ? P1b0 : P0b0;
                f2& b1 = (j2 & 1) ? P1b1 : P0b1;
                f2 wa0 = (yok0 & m0) ? a0 : zero;      // vmcnt wait lands here
                f2 wa1 = (yok1 & m0) ? a1 : zero;
                f2 wb0 = (yok0 & m1) ? b0 : zero;
                f2 wb1 = (yok1 & m1) ? b1 : zero;
                issue2(y0 + 4, a0, a1, b0, b1);        // refill: 2 pairs in flight

                __builtin_amdgcn_fence(__ATOMIC_ACQ_REL, "wavefront");
                __builtin_amdgcn_wave_barrier();
                st0[lane] = wa0;
                st1[lane] = wa1;
                if (lane < 10) { st0[64 + lane] = wb0; st1[64 + lane] = wb1; }
                __builtin_amdgcn_fence(__ATOMIC_ACQ_REL, "wavefront");
                __builtin_amdgcn_wave_barrier();

                // Horizontal 11-tap for BOTH rows, interleaved (independent
                // chains -> 2x ILP). Same-wave DS ordering guarantees RAW.
                f2 hmu0 = zero, hsq0 = zero, hmu1 = zero, hsq1 = zero;
                float hxx0 = 0.f, hxx1 = 0.f;
#pragma unroll
                for (int k = 0; k < WSZ; ++k) {
                    const float g = gw(k);
                    f2 p0 = st0[lane + k];
                    f2 p1 = st1[lane + k];
                    hmu0 += p0 * g;  hsq0 += (p0 * p0) * g;  hxx0 += (p0.x * p0.y) * g;
                    hmu1 += p1 * g;  hsq1 += (p1 * p1) * g;  hxx1 += (p1.x * p1.y) * g;
                }
                const int sE = 2 * j2;                 // staged row it0 slot
                const int sO = 2 * j2 + 1;             // staged row it0+1 slot
                rmu[sE] = hmu0; rsq[sE] = hsq0; rxx[sE] = hxx0;
                rmu[sO] = hmu1; rsq[sO] = hsq1; rxx[sO] = hxx1;

                // Vertical 11-tap + SSIM for the two completed output rows
                // (o0 = it0-10 needs slots (2*j2+2+k)%12; o1 = it0-9 needs
                // (2*j2+3+k)%12 — both static after unroll).
                if (it0 >= 10) {
                    f2 vmu0 = zero, vsq0 = zero, vmu1 = zero, vsq1 = zero;
                    float vxx0 = 0.f, vxx1 = 0.f;
#pragma unroll
                    for (int k = 0; k < WSZ; ++k) {
                        const float g = gw(k);
                        const int sA = (2 * j2 + 2 + k) % 12;
                        const int sB = (2 * j2 + 3 + k) % 12;
                        vmu0 += rmu[sA] * g; vsq0 += rsq[sA] * g; vxx0 += rxx[sA] * g;
                        vmu1 += rmu[sB] * g; vsq1 += rsq[sB] * g; vxx1 += rxx[sB] * g;
                    }
                    {
                        const float mu1 = vmu0.x, mu2 = vmu0.y;
                        const float mu11 = mu1 * mu1, mu22 = mu2 * mu2, mu12 = mu1 * mu2;
                        const float sig1 = vsq0.x - mu11;
                        const float sig2 = vsq0.y - mu22;
                        const float sig12 = vxx0 - mu12;
                        const float num = (2.f * mu12 + C1) * (2.f * sig12 + C2);
                        const float den = (mu11 + mu22 + C1) * (sig1 + sig2 + C2);
                        local += num * __builtin_amdgcn_rcpf(den);
                    }
                    {
                        const float mu1 = vmu1.x, mu2 = vmu1.y;
                        const float mu11 = mu1 * mu1, mu22 = mu2 * mu2, mu12 = mu1 * mu2;
                        const float sig1 = vsq1.x - mu11;
                        const float sig2 = vsq1.y - mu22;
                        const float sig12 = vxx1 - mu12;
                        const float num = (2.f * mu12 + C1) * (2.f * sig12 + C2);
                        const float den = (mu11 + mu22 + C1) * (sig1 + sig2 + C2);
                        local += num * __builtin_amdgcn_rcpf(den);
                    }
                }
            }
        }
    }

#pragma unroll
    for (int off = 32; off > 0; off >>= 1) local += __shfl_down(local, off);
    return local;
}

// All 4 scales in ONE dispatch (R5 structure). 128-thread blocks = 2
// independent waves on adjacent row strips. Scales interleaved in groups of
// 29 (16:8:4:1 matches per-channel block counts 32:16:8:2) so every scale is
// co-resident from t=0; small scales run inside scale-0's shadow.
// Each wave plain-stores its partial to its own slot -> no init kernel, no
// atomics, no device fences (R6 lesson: per-block threadfence+atomics cost
// ~80us of stall).
// __launch_bounds__(128, 2) — R9 FIX: R8's (128,4) let the allocator pick
// the 64-VGPR/8-wave occupancy step and SPILL the ~110-VGPR 2-row body
// (WRITE_SIZE 0.13 -> 77.6 MB, fused 127 -> 140us). Cap 256 lets it settle
// at the ~128-VGPR/4-wave step with zero spill; effective residency is
// grid-limited at ~2 waves/SIMD anyway, so the wider cap costs nothing.
__global__ __launch_bounds__(128, 2) void ssim_fused_kernel(
    const float* __restrict__ img1, const float* __restrict__ img2,
    const f2* __restrict__ p1, const f2* __restrict__ p2, const f2* __restrict__ p3,
    double* __restrict__ partials)
{
    __shared__ f2 st_all[2][160];          // per wave: 2 staging rows x 80
    const int lane = threadIdx.x & 63;
    const int wv   = threadIdx.x >> 6;
    f2* st = st_all[wv];

    const int i = blockIdx.x;
    const int g = i / 29;                  // magic-mul div
    const int r = i - g * 29;

    float local;
    if (r < 16) {                          // scale 0: RT=64, 512x512, planar
        const int l = g * 16 + r;
        local = ssim_body<64, true>(img1, img2, nullptr, 512, 512,
                                    l & 7, ((l >> 3) & 3) * 2 + wv, l >> 5, st, lane);
    } else if (r < 24) {                   // scale 1: RT=32, 256x256
        const int l = g * 8 + (r - 16);
        local = ssim_body<32, false>(nullptr, nullptr, p1, 256, 256,
                                     l & 3, ((l >> 2) & 3) * 2 + wv, l >> 4, st, lane);
    } else if (r < 28) {                   // scale 2: RT=16, 128x128
        const int l = g * 4 + (r - 24);
        local = ssim_body<16, false>(nullptr, nullptr, p2, 128, 128,
                                     l & 1, ((l >> 1) & 3) * 2 + wv, l >> 3, st, lane);
    } else {                               // scale 3: RT=16, 64x64
        const int l = g;
        local = ssim_body<16, false>(nullptr, nullptr, p3, 64, 64,
                                     0, (l & 1) * 2 + wv, l >> 1, st, lane);
    }
    if (lane == 0) partials[(size_t)i * 2 + wv] = (double)local;
}

// Single-block reduce of all per-wave partials; decodes wave->scale from the
// same group-of-29 mapping. ~45 KB of L2-hot doubles, few us.
__global__ __launch_bounds__(256) void finalize_kernel(
    const double* __restrict__ partials, float* __restrict__ out, int nw,
    double c0, double c1, double c2, double c3)
{
    double s[4] = {0.0, 0.0, 0.0, 0.0};
    for (int idx = threadIdx.x; idx < nw; idx += 256) {
        const int b = idx >> 1;
        const int g = b / 29;
        const int r = b - g * 29;
        const int sc = (r < 16) ? 0 : (r < 24) ? 1 : (r < 28) ? 2 : 3;
        s[sc] += partials[idx];
    }
    __shared__ double sm[4][256];
    sm[0][threadIdx.x] = s[0]; sm[1][threadIdx.x] = s[1];
    sm[2][threadIdx.x] = s[2]; sm[3][threadIdx.x] = s[3];
    __syncthreads();
    if (threadIdx.x == 0) {
        const double w[4] = {0.0448, 0.2856, 0.3001, 0.2363};
        const double cnt[4] = {c0, c1, c2, c3};
        double loss = 0.0;
#pragma unroll
        for (int sc = 0; sc < 4; ++sc) {
            double t = 0.0;
            for (int k = 0; k < 256; ++k) t += sm[sc][k];
            loss += w[sc] * (1.0 - t / cnt[sc]);
        }
        out[0] = (float)loss;
    }
}

extern "C" void kernel_launch(void* const* d_in, const int* in_sizes, int n_in,
                              void* d_out, int out_size, void* d_ws, size_t ws_size,
                              hipStream_t stream) {
    const float* img1 = (const float*)d_in[0];
    const float* img2 = (const float*)d_in[1];
    float* out = (float*)d_out;

    const int H0 = 512, W0 = 512;
    const int NC = in_sizes[0] / (H0 * W0);  // 48

    double* partials = (double*)d_ws;                 // NC*58*2 doubles (<64KB)
    f2* p1 = (f2*)((char*)d_ws + 65536);              // NC*256*256
    f2* p2 = p1 + (size_t)NC * 256 * 256;             // NC*128*128
    f2* p3 = p2 + (size_t)NC * 128 * 128;             // NC*64*64

    // Pyramid: 2 col-halves x 64 row-groups x NC channels, 1 wave each.
    pyramid_kernel<<<dim3(2, 64, NC), 64, 0, stream>>>(img1, img2, p1, p2, p3);

    // Fused SSIM: per channel 32+16+8+2 = 58 blocks = 2 groups of 29.
    const int NBLK = NC * 58;
    ssim_fused_kernel<<<dim3(NBLK), 128, 0, stream>>>(img1, img2, p1, p2, p3, partials);

    const double c0 = (double)NC * 512.0 * 512.0;
    const double c1 = (double)NC * 256.0 * 256.0;
    const double c2 = (double)NC * 128.0 * 128.0;
    const double c3 = (double)NC * 64.0 * 64.0;
    finalize_kernel<<<1, 256, 0, stream>>>(partials, out, NBLK * 2, c0, c1, c2, c3);
}

// Round 10
// 236.014 us; speedup vs baseline: 1.1013x; 1.0076x over previous
//
#include <hip/hip_runtime.h>

typedef float f2 __attribute__((ext_vector_type(2)));
typedef float f4 __attribute__((ext_vector_type(4)));

#define PAD 5
#define WSZ 11

// Precomputed normalized 11-tap Gaussian (sigma=1.5) — matches fp32 ref far
// within the 1.4e-2 threshold. Hard-coded to keep weights out of VGPRs.
__device__ __forceinline__ float gw(int k) {
    const float G[WSZ] = {
        0.0010283782f, 0.0075987580f, 0.0360007600f, 0.1093607000f,
        0.2130055600f, 0.2660117400f,
        0.2130055600f, 0.1093607000f, 0.0360007600f, 0.0075987580f, 0.0010283782f };
    return G[k];
}

// Pyramid pre-pass (R5-proven, ~22us = HBM roofline for its 134 MB): one wave
// per (col-half, 8-row group, channel) = 6144 waves. Lane owns 4 CONTIGUOUS
// cols -> every global load is a fully-coalesced wave-wide f4; all 16 loads
// issued up-front. Produces p1 (2x2), p2 (4x4), p3 (8x8 via one __shfl_xor
// pair-reduce).
__global__ __launch_bounds__(64) void pyramid_kernel(
    const float* __restrict__ img1, const float* __restrict__ img2,
    f2* __restrict__ p1, f2* __restrict__ p2, f2* __restrict__ p3)
{
    const int lane = threadIdx.x;        // owns raw cols cb*256 + lane*4 ..+3
    const int cb = blockIdx.x;           // column half (0/1)
    const int rb = blockIdx.y;           // 8-row group (0..63)
    const int z  = blockIdx.z;

    const size_t ibase = (size_t)z * 262144 + (size_t)(rb * 8) * 512 + cb * 256 + lane * 4;
    const float* b1 = img1 + ibase;
    const float* b2 = img2 + ibase;

    f4 A[8], B[8];
#pragma unroll
    for (int r = 0; r < 8; ++r) {        // 16 independent loads in flight
        A[r] = *(const f4*)(b1 + r * 512);
        B[r] = *(const f4*)(b2 + r * 512);
    }

    f2 u0, u1;
#pragma unroll
    for (int q = 0; q < 2; ++q) {        // q = p2 row within group
        f2 acc = {0.f, 0.f};
#pragma unroll
        for (int h = 0; h < 2; ++h) {    // p1 row within p2 row
            const int rp = q * 2 + h;
            f4 a0 = A[2 * rp], a1 = A[2 * rp + 1];
            f4 c0 = B[2 * rp], c1 = B[2 * rp + 1];
            f2 v0 = { (a0.x + a0.y + a1.x + a1.y) * 0.25f,
                      (c0.x + c0.y + c1.x + c1.y) * 0.25f };
            f2 v1 = { (a0.z + a0.w + a1.z + a1.w) * 0.25f,
                      (c0.z + c0.w + c1.z + c1.w) * 0.25f };
            *(f4*)(p1 + (size_t)z * 65536 + (size_t)(rb * 4 + rp) * 256
                       + cb * 128 + lane * 2) = (f4){ v0.x, v0.y, v1.x, v1.y };
            acc += v0 + v1;
        }
        f2 u = acc * 0.25f;              // p2 pixel (4x4 avg)
        p2[(size_t)z * 16384 + (size_t)(rb * 2 + q) * 128 + cb * 64 + lane] = u;
        if (q == 0) u0 = u; else u1 = u;
    }
    f2 t = u0 + u1;                       // lane's 2 p2 pixels
    t.x += __shfl_xor(t.x, 1);            // + neighbor lane's column
    t.y += __shfl_xor(t.y, 1);
    if ((lane & 1) == 0)
        p3[(size_t)z * 4096 + (size_t)rb * 64 + cb * 32 + (lane >> 1)] = t * 0.25f;
}

// Per-wave SSIM strip body, 2-ROW-PER-ITERATION (R9-proven, byte-identical).
// 64-col x RT-row strip. Each iteration stages and filters a PAIR of rows:
// two independent H-filter chains interleave in one tap loop (2x intra-wave
// ILP), fences/barriers and loop bookkeeping halve per row, pair-depth-2
// prefetch keeps 4 rows in flight. Horizontal 11-tap via two 80-wide private
// LDS rows (same-wave DS ordering; wavefront fences pin the compiler, emit no
// waitcnt -> prefetch loads stay in flight). Vertical 11-tap via a 12-deep
// register ring (static indices after unroll-by-6).
// [Lessons: R2/R6 occupancy-via-grid lose; R7 VALU->LDS trade loses; R8
//  64-VGPR cap spills this body; R4 pooling-at-consume loses.]
template<int RT, bool PLANAR>
__device__ __forceinline__ float ssim_body(
    const float* __restrict__ img1, const float* __restrict__ img2,
    const f2* __restrict__ pair,
    int H, int W, int bx, int sy, int z, f2* st, int lane)
{
    const int ox = bx * 64;
    const int r0 = sy * RT;
    const size_t base = (size_t)z * H * W;

    constexpr int NIT  = RT + 10;        // staged rows (even: RT even)
    constexpr int NIT2 = NIT / 2;        // row pairs
    const float C1 = 1e-4f, C2 = 9e-4f;

    // Per-lane column geometry (iteration-invariant).
    const int c0 = ox - PAD + lane;
    const bool m0 = (c0 >= 0) & (c0 < W);
    const int c0c = min(max(c0, 0), W - 1);
    const int c1 = ox + 59 + lane;                 // halo cols, lanes 0..9
    const bool m1 = (lane < 10) & (c1 < W);
    const int c1c = min(c1, W - 1);

    // Two prefetch slots, each holding a ROW PAIR (a=main col, b=halo col).
    f2 P0a0={0.f,0.f}, P0a1={0.f,0.f}, P0b0={0.f,0.f}, P0b1={0.f,0.f};
    f2 P1a0={0.f,0.f}, P1a1={0.f,0.f}, P1b0={0.f,0.f}, P1b1={0.f,0.f};

    auto issue2 = [&](int y, f2& A0, f2& A1, f2& B0, f2& B1) {
        const int ya = min(max(y, 0), H - 1);          // clamp; mask at consume
        const int yb = min(max(y + 1, 0), H - 1);
        const size_t ra = base + (size_t)ya * W;       // wave-uniform -> SALU
        const size_t rb = base + (size_t)yb * W;
        if (PLANAR) {
            A0 = (f2){ img1[ra + c0c], img2[ra + c0c] };
            A1 = (f2){ img1[rb + c0c], img2[rb + c0c] };
            if (lane < 10) {
                B0 = (f2){ img1[ra + c1c], img2[ra + c1c] };
                B1 = (f2){ img1[rb + c1c], img2[rb + c1c] };
            }
        } else {
            A0 = pair[ra + c0c];
            A1 = pair[rb + c0c];
            if (lane < 10) { B0 = pair[ra + c1c]; B1 = pair[rb + c1c]; }
        }
    };

    issue2(r0 - PAD + 0, P0a0, P0a1, P0b0, P0b1);   // pair 0
    issue2(r0 - PAD + 2, P1a0, P1a1, P1b0, P1b1);   // pair 1

    f2 rmu[12], rsq[12];
    float rxx[12];
    float local = 0.f;
    const f2 zero = {0.f, 0.f};
    f2* st0 = st;          // staging row for even staged-row index
    f2* st1 = st + 80;     // staging row for odd staged-row index

#pragma clang loop unroll(disable)
    for (int q0 = 0; q0 < NIT2; q0 += 6) {
#pragma unroll
        for (int j2 = 0; j2 < 6; ++j2) {
            const int i2 = q0 + j2;
            if (i2 < NIT2) {
                const int it0 = 2 * i2;                // absolute staged-row idx
                const int y0 = r0 - PAD + it0;
                const bool yok0 = (y0 >= 0) & (y0 < H);      // wave-uniform
                const bool yok1 = (y0 + 1 >= 0) & (y0 + 1 < H);

                f2& a0 = (j2 & 1) ? P1a0 : P0a0;       // static slot select
                f2& a1 = (j2 & 1) ? P1a1 : P0a1;
                f2& b0 = (j2 & 1) ? P1b0 : P0b0;
                f2& b1 = (j2 & 1) ? P1b1 : P0b1;
                f2 wa0 = (yok0 & m0) ? a0 : zero;      // vmcnt wait lands here
                f2 wa1 = (yok1 & m0) ? a1 : zero;
                f2 wb0 = (yok0 & m1) ? b0 : zero;
                f2 wb1 = (yok1 & m1) ? b1 : zero;
                issue2(y0 + 4, a0, a1, b0, b1);        // refill: 2 pairs in flight

                __builtin_amdgcn_fence(__ATOMIC_ACQ_REL, "wavefront");
                __builtin_amdgcn_wave_barrier();
                st0[lane] = wa0;
                st1[lane] = wa1;
                if (lane < 10) { st0[64 + lane] = wb0; st1[64 + lane] = wb1; }
                __builtin_amdgcn_fence(__ATOMIC_ACQ_REL, "wavefront");
                __builtin_amdgcn_wave_barrier();

                // Horizontal 11-tap for BOTH rows, interleaved (independent
                // chains -> 2x ILP). Same-wave DS ordering guarantees RAW.
                f2 hmu0 = zero, hsq0 = zero, hmu1 = zero, hsq1 = zero;
                float hxx0 = 0.f, hxx1 = 0.f;
#pragma unroll
                for (int k = 0; k < WSZ; ++k) {
                    const float g = gw(k);
                    f2 p0 = st0[lane + k];
                    f2 p1 = st1[lane + k];
                    hmu0 += p0 * g;  hsq0 += (p0 * p0) * g;  hxx0 += (p0.x * p0.y) * g;
                    hmu1 += p1 * g;  hsq1 += (p1 * p1) * g;  hxx1 += (p1.x * p1.y) * g;
                }
                const int sE = 2 * j2;                 // staged row it0 slot
                const int sO = 2 * j2 + 1;             // staged row it0+1 slot
                rmu[sE] = hmu0; rsq[sE] = hsq0; rxx[sE] = hxx0;
                rmu[sO] = hmu1; rsq[sO] = hsq1; rxx[sO] = hxx1;

                // Vertical 11-tap + SSIM for the two completed output rows
                // (o0 = it0-10 needs slots (2*j2+2+k)%12; o1 = it0-9 needs
                // (2*j2+3+k)%12 — both static after unroll).
                if (it0 >= 10) {
                    f2 vmu0 = zero, vsq0 = zero, vmu1 = zero, vsq1 = zero;
                    float vxx0 = 0.f, vxx1 = 0.f;
#pragma unroll
                    for (int k = 0; k < WSZ; ++k) {
                        const float g = gw(k);
                        const int sA = (2 * j2 + 2 + k) % 12;
                        const int sB = (2 * j2 + 3 + k) % 12;
                        vmu0 += rmu[sA] * g; vsq0 += rsq[sA] * g; vxx0 += rxx[sA] * g;
                        vmu1 += rmu[sB] * g; vsq1 += rsq[sB] * g; vxx1 += rxx[sB] * g;
                    }
                    {
                        const float mu1 = vmu0.x, mu2 = vmu0.y;
                        const float mu11 = mu1 * mu1, mu22 = mu2 * mu2, mu12 = mu1 * mu2;
                        const float sig1 = vsq0.x - mu11;
                        const float sig2 = vsq0.y - mu22;
                        const float sig12 = vxx0 - mu12;
                        const float num = (2.f * mu12 + C1) * (2.f * sig12 + C2);
                        const float den = (mu11 + mu22 + C1) * (sig1 + sig2 + C2);
                        local += num * __builtin_amdgcn_rcpf(den);
                    }
                    {
                        const float mu1 = vmu1.x, mu2 = vmu1.y;
                        const float mu11 = mu1 * mu1, mu22 = mu2 * mu2, mu12 = mu1 * mu2;
                        const float sig1 = vsq1.x - mu11;
                        const float sig2 = vsq1.y - mu22;
                        const float sig12 = vxx1 - mu12;
                        const float num = (2.f * mu12 + C1) * (2.f * sig12 + C2);
                        const float den = (mu11 + mu22 + C1) * (sig1 + sig2 + C2);
                        local += num * __builtin_amdgcn_rcpf(den);
                    }
                }
            }
        }
    }

#pragma unroll
    for (int off = 32; off > 0; off >>= 1) local += __shfl_down(local, off);
    return local;
}

// All 4 scales in ONE dispatch. R10: 256-thread blocks = 4 SAME-SCALE waves
// on adjacent row strips (was 128-thr/2-wave). Per channel this is exactly
// 16 s0 + 8 s1 + 4 s2 + 1 s3 = 29 blocks -> z = blockIdx/29, r = blockIdx%29.
// Single-variable test: measured occupancy has sat at ~1/3 of nominal across
// all rounds regardless of wave supply — if a per-CU workgroup-slot limit is
// the throttle, halving the workgroup count doubles resident waves with the
// per-wave hot path byte-identical. Same-scale packing keeps block durations
// uniform (R6's mixed-duration imbalance trap avoided).
// Each wave plain-stores its partial to its own slot -> no init kernel, no
// atomics, no device fences (R6 lesson). __launch_bounds__(256,2): same
// 256-VGPR cap R9's allocator settled at 76 under (R8: a 64-cap spills).
__global__ __launch_bounds__(256, 2) void ssim_fused_kernel(
    const float* __restrict__ img1, const float* __restrict__ img2,
    const f2* __restrict__ p1, const f2* __restrict__ p2, const f2* __restrict__ p3,
    double* __restrict__ partials)
{
    __shared__ f2 st_all[4][160];          // per wave: 2 staging rows x 80
    const int lane = threadIdx.x & 63;
    const int wv   = threadIdx.x >> 6;     // 0..3
    f2* st = st_all[wv];

    const int i = blockIdx.x;
    const int z = i / 29;                  // channel (magic-mul div)
    const int r = i - z * 29;

    float local;
    if (r < 16) {                          // scale 0: RT=64, 512x512, planar
        // 16 blocks/ch: bx = r&7, sy-quad = r>>3 -> sy = (r>>3)*4 + wv (0..7)
        local = ssim_body<64, true>(img1, img2, nullptr, 512, 512,
                                    r & 7, (r >> 3) * 4 + wv, z, st, lane);
    } else if (r < 24) {                   // scale 1: RT=32, 256x256
        const int l = r - 16;              // 8 blocks/ch: bx = l&3, sy = (l>>2)*4+wv
        local = ssim_body<32, false>(nullptr, nullptr, p1, 256, 256,
                                     l & 3, (l >> 2) * 4 + wv, z, st, lane);
    } else if (r < 28) {                   // scale 2: RT=16, 128x128
        const int l = r - 24;              // 4 blocks/ch: bx = l&1, sy = (l>>1)*4+wv
        local = ssim_body<16, false>(nullptr, nullptr, p2, 128, 128,
                                     l & 1, (l >> 1) * 4 + wv, z, st, lane);
    } else {                               // scale 3: RT=16, 64x64, 1 block/ch
        local = ssim_body<16, false>(nullptr, nullptr, p3, 64, 64,
                                     0, wv, z, st, lane);
    }
    if (lane == 0) partials[(size_t)i * 4 + wv] = (double)local;
}

// Single-block reduce of all per-wave partials; decodes wave->scale from the
// 29-blocks-per-channel mapping. ~45 KB of L2-hot doubles, few us.
__global__ __launch_bounds__(256) void finalize_kernel(
    const double* __restrict__ partials, float* __restrict__ out, int nw,
    double c0, double c1, double c2, double c3)
{
    double s[4] = {0.0, 0.0, 0.0, 0.0};
    for (int idx = threadIdx.x; idx < nw; idx += 256) {
        const int b = idx >> 2;            // block index (4 waves/block)
        const int g = b / 29;
        const int r = b - g * 29;
        const int sc = (r < 16) ? 0 : (r < 24) ? 1 : (r < 28) ? 2 : 3;
        s[sc] += partials[idx];
    }
    __shared__ double sm[4][256];
    sm[0][threadIdx.x] = s[0]; sm[1][threadIdx.x] = s[1];
    sm[2][threadIdx.x] = s[2]; sm[3][threadIdx.x] = s[3];
    __syncthreads();
    if (threadIdx.x == 0) {
        const double w[4] = {0.0448, 0.2856, 0.3001, 0.2363};
        const double cnt[4] = {c0, c1, c2, c3};
        double loss = 0.0;
#pragma unroll
        for (int sc = 0; sc < 4; ++sc) {
            double t = 0.0;
            for (int k = 0; k < 256; ++k) t += sm[sc][k];
            loss += w[sc] * (1.0 - t / cnt[sc]);
        }
        out[0] = (float)loss;
    }
}

extern "C" void kernel_launch(void* const* d_in, const int* in_sizes, int n_in,
                              void* d_out, int out_size, void* d_ws, size_t ws_size,
                              hipStream_t stream) {
    const float* img1 = (const float*)d_in[0];
    const float* img2 = (const float*)d_in[1];
    float* out = (float*)d_out;

    const int H0 = 512, W0 = 512;
    const int NC = in_sizes[0] / (H0 * W0);  // 48

    double* partials = (double*)d_ws;                 // NC*29*4 doubles (<64KB)
    f2* p1 = (f2*)((char*)d_ws + 65536);              // NC*256*256
    f2* p2 = p1 + (size_t)NC * 256 * 256;             // NC*128*128
    f2* p3 = p2 + (size_t)NC * 128 * 128;             // NC*64*64

    // Pyramid: 2 col-halves x 64 row-groups x NC channels, 1 wave each.
    pyramid_kernel<<<dim3(2, 64, NC), 64, 0, stream>>>(img1, img2, p1, p2, p3);

    // Fused SSIM: exactly 29 same-scale 4-wave blocks per channel.
    const int NBLK = NC * 29;
    ssim_fused_kernel<<<dim3(NBLK), 256, 0, stream>>>(img1, img2, p1, p2, p3, partials);

    const double c0 = (double)NC * 512.0 * 512.0;
    const double c1 = (double)NC * 256.0 * 256.0;
    const double c2 = (double)NC * 128.0 * 128.0;
    const double c3 = (double)NC * 64.0 * 64.0;
    finalize_kernel<<<1, 256, 0, stream>>>(partials, out, NBLK * 4, c0, c1, c2, c3);
}